// Round 5
// baseline (121.146 us; speedup 1.0000x reference)
//
#include <hip/hip_runtime.h>

#define TPB 256

__global__ __launch_bounds__(TPB, 4) void fused_shift_conv(const float* __restrict__ x,
                                                           const float* __restrict__ Wg,
                                                           float* __restrict__ out) {
    // block handles one (n, p) output row
    const int bid = blockIdx.x;
    const int p = bid % 56;
    const int n = bid / 56;
    const int P = (p + 55) % 56;   // source spatial row (circular roll +1 along p)

    __shared__ float sm[64 * 57];  // staging t[r][col]; reused as [ch][57] for output transpose

    const int tid = threadIdx.x;
    // tid = q*64 + kp*32 + j  (q wave-uniform)
    const int j  = tid & 31;        // group 0..31
    const int kp = (tid >> 5) & 1;  // k-pair: k = 2*kp + kk
    const int q  = tid >> 6;        // column quarter: outputs o in [14q, 14q+13]
    const int cb = q * 14;

    // ---- W loads first (L2-resident; k adjacent -> float2) ----
    float wt[3][2][3][2];
    {
        const float2* W2 = reinterpret_cast<const float2*>(Wg);
#pragma unroll
        for (int i = 0; i < 3; ++i)
#pragma unroll
            for (int m = 0; m < 2; ++m)
#pragma unroll
                for (int l = 0; l < 3; ++l) {
                    const float2 w = W2[(((j * 3 + i) * 2 + m) * 3 + l) * 2 + kp];
                    wt[i][m][l][0] = w.x;
                    wt[i][m][l][1] = w.y;
                }
    }

    // ---- stage: sm[r][col] = x[n, r, P, col] + x[n, r+64, P, col] ----
    {
        const float4* x4 = reinterpret_cast<const float4*>(x);
#pragma unroll
        for (int it = 0; it < 4; ++it) {
            const int idx = tid + it * TPB;
            if (idx < 896) {
                const int r = idx / 14;
                const int v = idx - r * 14;
                const size_t base = (size_t)(n * 128 + r) * 784 + (size_t)P * 14 + (size_t)v;
                const float4 a = x4[base];
                const float4 b = x4[base + (size_t)64 * 784];
                const int s = r * 57 + v * 4;
                sm[s + 0] = a.x + b.x;
                sm[s + 1] = a.y + b.y;
                sm[s + 2] = a.z + b.z;
                sm[s + 3] = a.w + b.w;
            }
        }
    }
    __syncthreads();

    // ---- compute: 14 cols x 2 channels per thread ----
    // val[d] = t[col cb-2+d], d=0..15; masks: q=0 -> val[0]=0 (o=0,l=0), val[1]=row[55];
    //                                   q=3 -> val[15]=0 (o=55,l=2)
    float acc[2][14];
#pragma unroll
    for (int kk = 0; kk < 2; ++kk)
#pragma unroll
        for (int u = 0; u < 14; ++u) acc[kk][u] = 0.f;

#pragma unroll
    for (int i = 0; i < 3; ++i) {
        const int g = j + i - 1;
        if ((unsigned)g < 32u) {
#pragma unroll
            for (int m = 0; m < 2; ++m) {
                const float* row = &sm[(2 * g + m) * 57];
                const float* rowq = row + cb - 2;   // valid for d>=2 when q==0
                float val[16];
                if (q == 0) {
                    val[0] = 0.f;
                    val[1] = row[55];
#pragma unroll
                    for (int d = 2; d < 16; ++d) val[d] = rowq[d];
                } else {
#pragma unroll
                    for (int d = 0; d < 16; ++d) val[d] = rowq[d];
                    if (q == 3) val[15] = 0.f;
                }
#pragma unroll
                for (int l = 0; l < 3; ++l) {
                    const float w0 = wt[i][m][l][0];
                    const float w1 = wt[i][m][l][1];
#pragma unroll
                    for (int u = 0; u < 14; ++u) {
                        acc[0][u] += w0 * val[u + l];
                        acc[1][u] += w1 * val[u + l];
                    }
                }
            }
        }
    }

    // ---- 2-pass transposed store via sm[ch][57] ----
    const int c0 = j * 4 + kp * 2;   // first of this thread's 2 channels
    const int chalf = c0 >> 6;
    float4* o4 = reinterpret_cast<float4*>(out);

#pragma unroll
    for (int half = 0; half < 2; ++half) {
        __syncthreads();             // compute reads / previous pass reads done
        if (chalf == half) {
#pragma unroll
            for (int kk = 0; kk < 2; ++kk) {
                float* orow = &sm[((c0 & 63) + kk) * 57 + cb];
#pragma unroll
                for (int u = 0; u < 14; ++u) orow[u] = acc[kk][u];
            }
        }
        __syncthreads();
        // 64 ch x 14 float4 = 896 float4, coalesced 224B runs per channel
#pragma unroll
        for (int it = 0; it < 4; ++it) {
            const int idx = tid + it * TPB;
            if (idx < 896) {
                const int ch = idx / 14;
                const int v = idx - ch * 14;
                const float* s = &sm[ch * 57 + v * 4];
                float4 v4;
                v4.x = s[0]; v4.y = s[1]; v4.z = s[2]; v4.w = s[3];
                o4[(size_t)(n * 128 + half * 64 + ch) * 784 + (size_t)p * 14 + (size_t)v] = v4;
            }
        }
    }
}

extern "C" void kernel_launch(void* const* d_in, const int* in_sizes, int n_in,
                              void* d_out, int out_size, void* d_ws, size_t ws_size,
                              hipStream_t stream) {
    const float* x = (const float*)d_in[0];
    const float* W = (const float*)d_in[1];
    float* out = (float*)d_out;
    const int n = in_sizes[0] / (128 * 56 * 56);   // 128
    const int grid = n * 56;                        // one block per (n, p)
    fused_shift_conv<<<grid, TPB, 0, stream>>>(x, W, out);
}

// Round 6
// 115.483 us; speedup vs baseline: 1.0490x; 1.0490x over previous
//
#include <hip/hip_runtime.h>

#define TPB 256
#define RS4 15   // row stride in float4 units (60 floats, odd in f4-space -> conflict-free b128)

__global__ __launch_bounds__(TPB) void fused_shift_conv(const float* __restrict__ x,
                                                        const float* __restrict__ Wg,
                                                        float* __restrict__ out) {
    // block handles one (n, p) output row
    const int bid = blockIdx.x;
    const int p = bid % 56;
    const int n = bid / 56;
    const int P = (p + 55) % 56;   // source spatial row (circular roll +1 along p)

    __shared__ float4 sm4[64 * RS4];           // staging t[r][col]; reused for output transpose
    float* const sm = reinterpret_cast<float*>(sm4);

    const int tid = threadIdx.x;
    const int h = tid & 1;         // o-half: 0 -> o 0..27, 1 -> o 28..55
    const int c = tid >> 1;        // output channel 0..127
    const int j = c >> 2;          // group
    const int k = c & 3;

    // ---- W loads first: L2-resident, latency hides under x staging ----
    float wt[3][2][3];
#pragma unroll
    for (int i = 0; i < 3; ++i)
#pragma unroll
        for (int m = 0; m < 2; ++m)
#pragma unroll
            for (int l = 0; l < 3; ++l)
                wt[i][m][l] = Wg[(((j * 3 + i) * 2 + m) * 3 + l) * 4 + k];

    // ---- stage: sm[r][0..55] = x[n, r, P, :] + x[n, r+64, P, :]  (b128 writes, no conflicts) ----
    {
        const float4* x4 = reinterpret_cast<const float4*>(x);
#pragma unroll
        for (int it = 0; it < 4; ++it) {
            const int idx = tid + it * TPB;
            if (idx < 896) {
                const int r = idx / 14;
                const int v = idx - r * 14;
                const size_t base = (size_t)(n * 128 + r) * 784 + (size_t)P * 14 + (size_t)v;
                const float4 a = x4[base];
                const float4 b = x4[base + (size_t)64 * 784];
                float4 s;
                s.x = a.x + b.x; s.y = a.y + b.y; s.z = a.z + b.z; s.w = a.w + b.w;
                sm4[r * RS4 + v] = s;
            }
        }
    }
    __syncthreads();

    // ---- compute: 28 outputs per thread, linear LDS window (no modulo) ----
    //   h=0: val[0]=0 (o=0,l=0 pad), val[1]=row[55] (circular), val[2..29]=row[0..27]
    //   h=1: val[0]=row[26], val[1]=row[27], val[2..28]=row[28..54], val[29]=0 (o=55,l=2 pad)
    const int sbase = h * 28 - 2;
    const int sp1 = h ? 27 : 55;

    float acc[28];
#pragma unroll
    for (int u = 0; u < 28; ++u) acc[u] = 0.f;

#pragma unroll
    for (int i = 0; i < 3; ++i) {
        const int g = j + i - 1;
        if ((unsigned)g < 32u) {
#pragma unroll
            for (int m = 0; m < 2; ++m) {
                const float* row = &sm[(2 * g + m) * 60];
                float val[30];
                const float v26 = row[26];
                const float v27 = row[27];
                val[0]  = h ? v26 : 0.f;
                val[1]  = row[sp1];
                val[29] = h ? 0.f : v27;
#pragma unroll
                for (int d = 2; d < 29; ++d) val[d] = row[sbase + d];

                const float w0 = wt[i][m][0];
                const float w1 = wt[i][m][1];
                const float w2 = wt[i][m][2];
#pragma unroll
                for (int u = 0; u < 28; ++u)
                    acc[u] += w0 * val[u] + w1 * val[u + 1] + w2 * val[u + 2];
            }
        }
    }

    // ---- 2-pass transposed store, all-float4 through LDS ----
    const int chalf = c >> 6;      // which channel-half this thread's outputs belong to
    const int cr = c & 63;
    float4* o4 = reinterpret_cast<float4*>(out);

#pragma unroll
    for (int half = 0; half < 2; ++half) {
        __syncthreads();           // compute reads / previous pass reads done
        if (chalf == half) {
#pragma unroll
            for (int u4 = 0; u4 < 7; ++u4) {
                float4 v4;
                v4.x = acc[4 * u4 + 0];
                v4.y = acc[4 * u4 + 1];
                v4.z = acc[4 * u4 + 2];
                v4.w = acc[4 * u4 + 3];
                sm4[cr * RS4 + h * 7 + u4] = v4;   // odd f4-stride -> conflict-free
            }
        }
        __syncthreads();
        // 64 ch x 14 float4 = 896, coalesced 224B runs per channel
#pragma unroll
        for (int it = 0; it < 4; ++it) {
            const int idx = tid + it * TPB;
            if (idx < 896) {
                const int ch = idx / 14;
                const int v = idx - ch * 14;
                o4[(size_t)(n * 128 + half * 64 + ch) * 784 + (size_t)p * 14 + (size_t)v] =
                    sm4[ch * RS4 + v];
            }
        }
    }
}

extern "C" void kernel_launch(void* const* d_in, const int* in_sizes, int n_in,
                              void* d_out, int out_size, void* d_ws, size_t ws_size,
                              hipStream_t stream) {
    const float* x = (const float*)d_in[0];
    const float* W = (const float*)d_in[1];
    float* out = (float*)d_out;
    const int n = in_sizes[0] / (128 * 56 * 56);   // 128
    const int grid = n * 56;                        // one block per (n, p)
    fused_shift_conv<<<grid, TPB, 0, stream>>>(x, W, out);
}

// Round 7
// 114.750 us; speedup vs baseline: 1.0557x; 1.0064x over previous
//
#include <hip/hip_runtime.h>

#define TPB 256

__global__ __launch_bounds__(TPB, 4) void fused_shift_conv(const float* __restrict__ x,
                                                           const float* __restrict__ Wg,
                                                           float* __restrict__ out) {
    // block handles one (n, p) output row
    const int bid = blockIdx.x;
    const int p = bid % 56;
    const int n = bid / 56;
    const int P = (p + 55) % 56;   // source spatial row (circular roll +1 along p)

    // 128 rows x 15 float4 = 30,720 B. Staging uses rows 0..63; output transpose uses all 128.
    __shared__ float4 sm4[128 * 15];

    const int tid = threadIdx.x;
    const int h = tid & 1;         // o-half: 0 -> o 0..27, 1 -> o 28..55
    const int c = tid >> 1;        // output channel 0..127
    const int j = c >> 2;          // group
    const int k = c & 3;

    // ---- W loads first: L2-resident, latency hides under x staging ----
    float wt[3][2][3];
#pragma unroll
    for (int i = 0; i < 3; ++i)
#pragma unroll
        for (int m = 0; m < 2; ++m)
#pragma unroll
            for (int l = 0; l < 3; ++l)
                wt[i][m][l] = Wg[(((j * 3 + i) * 2 + m) * 3 + l) * 4 + k];

    // ---- stage: sm[r][0..55] = x[n, r, P, :] + x[n, r+64, P, :]  (b128, conflict-free) ----
    {
        const float4* x4 = reinterpret_cast<const float4*>(x);
#pragma unroll
        for (int it = 0; it < 4; ++it) {
            const int idx = tid + it * TPB;
            if (idx < 896) {
                const int r = idx / 14;
                const int v = idx - r * 14;
                const size_t base = (size_t)(n * 128 + r) * 784 + (size_t)P * 14 + (size_t)v;
                const float4 a = x4[base];
                const float4 b = x4[base + (size_t)64 * 784];
                float4 s;
                s.x = a.x + b.x; s.y = a.y + b.y; s.z = a.z + b.z; s.w = a.w + b.w;
                sm4[r * 15 + v] = s;
            }
        }
    }
    __syncthreads();

    // ---- compute: 28 outputs per thread, all-b128 LDS reads ----
    // f4 window (per lane): h=0 loads f4 {13, 0..6} -> cols {52..55, 0..27} (wrap block gives
    // the circular tap col55); h=1 loads f4 {6..13} -> cols {24..55}.
    // Unified indexing: va[d] = fe[d+2], d=0..29, then 2 boundary fixups:
    //   h=0: va[0] -> 0   (o=0,l=0 zero-pad; fe[2]=col54 unused)
    //   h=1: va[29] -> 0  (o=55,l=2 zero-pad; fe[31]=col55 unused)
    const int q0 = h ? 6 : 13;     // f4 index of first load
    const int qb = h ? 6 : -1;     // base for loads 1..7: f4 index = qb + q

    float acc[28];
#pragma unroll
    for (int u = 0; u < 28; ++u) acc[u] = 0.f;

#pragma unroll
    for (int i = 0; i < 3; ++i) {
        const int g = j + i - 1;
        if ((unsigned)g < 32u) {
#pragma unroll
            for (int m = 0; m < 2; ++m) {
                const float4* row4 = &sm4[(2 * g + m) * 15];
                float fe[32];
                {
                    const float4 t = row4[q0];
                    fe[0] = t.x; fe[1] = t.y; fe[2] = t.z; fe[3] = t.w;
                }
#pragma unroll
                for (int q = 1; q < 8; ++q) {
                    const float4 t = row4[qb + q];
                    fe[4 * q + 0] = t.x; fe[4 * q + 1] = t.y;
                    fe[4 * q + 2] = t.z; fe[4 * q + 3] = t.w;
                }
                float va[30];
#pragma unroll
                for (int d = 0; d < 30; ++d) va[d] = fe[d + 2];
                va[0]  = h ? va[0] : 0.f;
                va[29] = h ? 0.f : va[29];

                const float w0 = wt[i][m][0];
                const float w1 = wt[i][m][1];
                const float w2 = wt[i][m][2];
#pragma unroll
                for (int u = 0; u < 28; ++u)
                    acc[u] += w0 * va[u] + w1 * va[u + 1] + w2 * va[u + 2];
            }
        }
    }

    // ---- single-pass transposed store: all 128 channels through sm4[128][15] ----
    __syncthreads();               // all compute reads of staging done
#pragma unroll
    for (int u4 = 0; u4 < 7; ++u4) {
        float4 v4;
        v4.x = acc[4 * u4 + 0];
        v4.y = acc[4 * u4 + 1];
        v4.z = acc[4 * u4 + 2];
        v4.w = acc[4 * u4 + 3];
        sm4[c * 15 + h * 7 + u4] = v4;
    }
    __syncthreads();
    // 128 ch x 14 f4 = 1792 = 7 per thread; coalesced 224B runs per channel
    float4* o4 = reinterpret_cast<float4*>(out);
#pragma unroll
    for (int it = 0; it < 7; ++it) {
        const int idx = tid + it * TPB;
        const int ch = idx / 14;
        const int v = idx - ch * 14;
        o4[(size_t)(n * 128 + ch) * 784 + (size_t)p * 14 + (size_t)v] = sm4[ch * 15 + v];
    }
}

extern "C" void kernel_launch(void* const* d_in, const int* in_sizes, int n_in,
                              void* d_out, int out_size, void* d_ws, size_t ws_size,
                              hipStream_t stream) {
    const float* x = (const float*)d_in[0];
    const float* W = (const float*)d_in[1];
    float* out = (float*)d_out;
    const int n = in_sizes[0] / (128 * 56 * 56);   // 128
    const int grid = n * 56;                        // one block per (n, p)
    fused_shift_conv<<<grid, TPB, 0, stream>>>(x, W, out);
}